// Round 4
// baseline (664.821 us; speedup 1.0000x reference)
//
#include <hip/hip_runtime.h>
#include <math.h>

#define N_NODES 50000
#define IN_DIM  1000
#define HIDDEN  256
#define N_EDGES 1600000
#define KPAD    1024
#define NBLK    196      // ceil(50000/256)

typedef short bf16x8 __attribute__((ext_vector_type(8)));
typedef float f32x16 __attribute__((ext_vector_type(16)));
typedef unsigned int u32x4 __attribute__((ext_vector_type(4)));

__device__ __forceinline__ unsigned short f2bf_rne(float f) {
    unsigned u = __builtin_bit_cast(unsigned, f);
    unsigned r = (u + 0x7FFFu + ((u >> 16) & 1u)) >> 16;
    return (unsigned short)r;
}
__device__ __forceinline__ float bf2f(unsigned short b) {
    unsigned u = ((unsigned)b) << 16;
    return __builtin_bit_cast(float, u);
}
__device__ __forceinline__ unsigned cvt_pk_bf16(float a, float b) {
    unsigned r;
    asm("v_cvt_pk_bf16_f32 %0, %1, %2" : "=v"(r) : "v"(a), "v"(b));
    return r;   // [15:0]=bf16(a), [31:16]=bf16(b)
}

// ---------------- degree histogram ----------------
__global__ void hist_kernel(const int* __restrict__ ei, int* __restrict__ cnt) {
    int e = blockIdx.x * blockDim.x + threadIdx.x;
    int stride = gridDim.x * blockDim.x;
    for (; e < N_EDGES; e += stride) {
        int d = ei[N_EDGES + e];
        if ((unsigned)d < N_NODES) atomicAdd(&cnt[d], 1);
    }
}

// ---------------- 3-phase scan ----------------
__global__ __launch_bounds__(256) void scan_sums(const int* __restrict__ cnt, int* __restrict__ bsum) {
    __shared__ int s[256];
    int t = threadIdx.x;
    int i = blockIdx.x * 256 + t;
    s[t] = (i < N_NODES) ? cnt[i] : 0;
    __syncthreads();
    #pragma unroll
    for (int off = 128; off > 0; off >>= 1) {
        if (t < off) s[t] += s[t + off];
        __syncthreads();
    }
    if (t == 0) bsum[blockIdx.x] = s[0];
}

__global__ __launch_bounds__(256) void scan_top(int* __restrict__ bsum) {
    __shared__ int s[256];
    int t = threadIdx.x;
    int v = (t < NBLK) ? bsum[t] : 0;
    s[t] = v;
    __syncthreads();
    for (int off = 1; off < 256; off <<= 1) {
        int x = (t >= off) ? s[t - off] : 0;
        __syncthreads();
        s[t] += x;
        __syncthreads();
    }
    if (t < NBLK) bsum[t] = s[t] - v;   // exclusive
}

__global__ __launch_bounds__(256) void scan_write(const int* __restrict__ cnt, const int* __restrict__ bsum,
                                                  int* __restrict__ rowoff, int* __restrict__ cursor,
                                                  float* __restrict__ dinv) {
    __shared__ int s[256];
    int t = threadIdx.x;
    int i = blockIdx.x * 256 + t;
    int v = (i < N_NODES) ? cnt[i] : 0;
    s[t] = v;
    __syncthreads();
    for (int off = 1; off < 256; off <<= 1) {
        int x = (t >= off) ? s[t - off] : 0;
        __syncthreads();
        s[t] += x;
        __syncthreads();
    }
    if (i < N_NODES) {
        int ro = bsum[blockIdx.x] + s[t] - v;   // exclusive
        rowoff[i] = ro;
        cursor[i] = ro;
        dinv[i]  = rsqrtf((float)v + 1.0f);
    }
}

// ---------------- counting-sort scatter ----------------
__global__ void scatter_kernel(const int* __restrict__ ei,
                               int* __restrict__ cursor, int* __restrict__ csr) {
    int e = blockIdx.x * blockDim.x + threadIdx.x;
    int stride = gridDim.x * blockDim.x;
    for (; e < N_EDGES; e += stride) {
        int s = ei[e];
        int d = ei[N_EDGES + e];
        if ((unsigned)d < N_NODES && (unsigned)s < N_NODES) {
            int pos = atomicAdd(&cursor[d], 1);
            csr[pos] = s;
        }
    }
}

// ---------------- W1 split+transpose: Wt_h/Wt_l [256 cols][1024 k] bf16 ----------------
__global__ __launch_bounds__(256) void wsplit_kernel(const float* __restrict__ W1,
                                                     unsigned short* __restrict__ Wth,
                                                     unsigned short* __restrict__ Wtl) {
    int idx = blockIdx.x * 256 + threadIdx.x;   // 256*1024 total
    int c = idx >> 10, k = idx & 1023;
    float v = (k < IN_DIM) ? W1[(size_t)k * HIDDEN + c] : 0.0f;
    unsigned short hb = f2bf_rne(v);
    unsigned short lb = f2bf_rne(v - bf2f(hb));
    Wth[idx] = hb;
    Wtl[idx] = lb;
}

// ---------------- GEMM1 (MFMA, 3-product bf16 split, no LDS) ----------------
// 32 rows x 256 cols per block; 2 waves, wave w owns cols w*128..+127
// grid = 1563 blocks -> ~12 waves/CU (latency hiding), acc = 64 VGPR
__global__ __launch_bounds__(128, 3) void gemm1_mfma(const float* __restrict__ X,
                                                     const unsigned short* __restrict__ Wth,
                                                     const unsigned short* __restrict__ Wtl,
                                                     const float* __restrict__ dinv,
                                                     unsigned short* __restrict__ G1b) {
    const int tid = threadIdx.x;
    const int w  = tid >> 6;
    const int l  = tid & 63;
    const int lr = l & 31;    // A-row / B-col within frag
    const int lq = l >> 5;    // k half-slot
    const int m0 = blockIdx.x * 32;

    f32x16 acc[4] = {};

    const int arow = m0 + lr;
    const int rc = arow < N_NODES ? arow : N_NODES - 1;
    const float* ap = X + (size_t)rc * IN_DIM + lq * 8;

    for (int step = 0; step < 63; ++step) {       // ceil(1000/16)
        const int kb = step * 16 + lq * 8;
        // ---- A fragment: load 8 fp32, split hi/lo bf16 via cvt_pk ----
        float4 f0 = make_float4(0.f,0.f,0.f,0.f), f1 = f0;
        if (kb < IN_DIM) {                         // false only at step62/lq1
            f0 = *(const float4*)(ap);
            f1 = *(const float4*)(ap + 4);
        }
        float f[8] = {f0.x,f0.y,f0.z,f0.w,f1.x,f1.y,f1.z,f1.w};
        u32x4 hw, lw;
        #pragma unroll
        for (int j = 0; j < 4; ++j) {
            unsigned h = cvt_pk_bf16(f[2*j], f[2*j+1]);
            float hf0 = __builtin_bit_cast(float, h << 16);
            float hf1 = __builtin_bit_cast(float, h & 0xFFFF0000u);
            unsigned lo = cvt_pk_bf16(f[2*j] - hf0, f[2*j+1] - hf1);
            hw[j] = h; lw[j] = lo;
        }
        bf16x8 ah = __builtin_bit_cast(bf16x8, hw);
        bf16x8 al = __builtin_bit_cast(bf16x8, lw);

        // ---- B fragments (L2-resident 1 MB) ----
        bf16x8 bh[4], bl[4];
        #pragma unroll
        for (int ni = 0; ni < 4; ++ni) {
            int c = w * 128 + ni * 32 + lr;
            bh[ni] = *(const bf16x8*)(Wth + (size_t)c * KPAD + kb);
            bl[ni] = *(const bf16x8*)(Wtl + (size_t)c * KPAD + kb);
        }
        #pragma unroll
        for (int ni = 0; ni < 4; ++ni) {
            acc[ni] = __builtin_amdgcn_mfma_f32_32x32x16_bf16(ah, bh[ni], acc[ni], 0, 0, 0);
            acc[ni] = __builtin_amdgcn_mfma_f32_32x32x16_bf16(ah, bl[ni], acc[ni], 0, 0, 0);
            acc[ni] = __builtin_amdgcn_mfma_f32_32x32x16_bf16(al, bh[ni], acc[ni], 0, 0, 0);
        }
        ap += 16;
    }

    // C/D layout (m74/m101): col = lane&31, row = (reg&3) + 8*(reg>>2) + 4*(lane>>5)
    #pragma unroll
    for (int r = 0; r < 16; ++r) {
        int row = m0 + (r & 3) + 8 * (r >> 2) + 4 * lq;
        if (row >= N_NODES) continue;
        float dv = dinv[row];
        #pragma unroll
        for (int ni = 0; ni < 4; ++ni) {
            int col = w * 128 + ni * 32 + lr;
            G1b[(size_t)row * HIDDEN + col] = f2bf_rne(dv * acc[ni][r]);
        }
    }
}

// ---------------- fused agg1 + gemm2:  g2 = dinv * (relu(dinv*(g1[d]+sum g1[src])+b1) @ W2)
__global__ __launch_bounds__(256) void agg1g2_kernel(const unsigned short* __restrict__ G,
                                                     const int* __restrict__ csr,
                                                     const int* __restrict__ rowoff,
                                                     const int* __restrict__ cnt,
                                                     const float* __restrict__ dinv,
                                                     const float* __restrict__ b1,
                                                     const float* __restrict__ W2,
                                                     float* __restrict__ G2) {
    __shared__ float2 wl[HIDDEN];
    int tid = threadIdx.x;
    wl[tid] = make_float2(W2[tid * 2], W2[tid * 2 + 1]);
    __syncthreads();
    int wave = tid >> 6;
    int lane = tid & 63;
    int d = blockIdx.x * 4 + wave;
    if (d >= N_NODES) return;
    int c0 = lane * 4;
    ushort4 sv = *(const ushort4*)&G[(size_t)d * HIDDEN + c0];
    float ax = bf2f(sv.x), ay = bf2f(sv.y), az = bf2f(sv.z), aw = bf2f(sv.w);
    int beg = rowoff[d], num = cnt[d];
    for (int e = 0; e < num; ++e) {
        int s = csr[beg + e];
        ushort4 v = *(const ushort4*)&G[(size_t)s * HIDDEN + c0];
        ax += bf2f(v.x); ay += bf2f(v.y); az += bf2f(v.z); aw += bf2f(v.w);
    }
    float dv = dinv[d];
    float4 bb = *(const float4*)&b1[c0];
    float zx = fmaxf(dv * ax + bb.x, 0.f);
    float zy = fmaxf(dv * ay + bb.y, 0.f);
    float zz = fmaxf(dv * az + bb.z, 0.f);
    float zw = fmaxf(dv * aw + bb.w, 0.f);
    float2 w0 = wl[c0], w1 = wl[c0 + 1], w2_ = wl[c0 + 2], w3 = wl[c0 + 3];
    float a0 = zx * w0.x + zy * w1.x + zz * w2_.x + zw * w3.x;
    float a1 = zx * w0.y + zy * w1.y + zz * w2_.y + zw * w3.y;
    #pragma unroll
    for (int off = 32; off; off >>= 1) {
        a0 += __shfl_xor(a0, off, 64);
        a1 += __shfl_xor(a1, off, 64);
    }
    if (lane == 0) {
        G2[d * 2 + 0] = dv * a0;
        G2[d * 2 + 1] = dv * a1;
    }
}

// ---------------- agg2 ----------------
__global__ __launch_bounds__(256) void agg2_kernel(const float* __restrict__ G2,
                                                   const int* __restrict__ csr,
                                                   const int* __restrict__ rowoff,
                                                   const int* __restrict__ cnt,
                                                   const float* __restrict__ dinv,
                                                   const float* __restrict__ b2,
                                                   float* __restrict__ out) {
    int wave = threadIdx.x >> 6, lane = threadIdx.x & 63;
    int d = blockIdx.x * 4 + wave;
    if (d >= N_NODES) return;
    int beg = rowoff[d], num = cnt[d];
    float a0 = 0.f, a1 = 0.f;
    for (int e = lane; e < num; e += 64) {
        int s = csr[beg + e];
        float2 g = *(const float2*)&G2[s * 2];
        a0 += g.x; a1 += g.y;
    }
    #pragma unroll
    for (int off = 32; off; off >>= 1) {
        a0 += __shfl_xor(a0, off, 64);
        a1 += __shfl_xor(a1, off, 64);
    }
    if (lane == 0) {
        float2 self = *(const float2*)&G2[d * 2];
        float dv = dinv[d];
        out[d * 2 + 0] = dv * (a0 + self.x) + b2[0];
        out[d * 2 + 1] = dv * (a1 + self.y) + b2[1];
    }
}

// ---------------- workspace layout (bytes) ----------------
#define OFF_CNT     0u
#define OFF_ROWOFF  262144u
#define OFF_CURSOR  524288u
#define OFF_DINV    786432u
#define OFF_BSUM    1048576u
#define OFF_CSR     1310720u
#define OFF_WTH     8388608u
#define OFF_WTL     8912896u
#define OFF_G1B     9437184u
#define OFF_G2      35651584u
// total ~36.1 MB

extern "C" void kernel_launch(void* const* d_in, const int* in_sizes, int n_in,
                              void* d_out, int out_size, void* d_ws, size_t ws_size,
                              hipStream_t stream) {
    const float* x  = (const float*)d_in[0];
    const float* W1 = (const float*)d_in[1];
    const float* b1 = (const float*)d_in[2];
    const float* W2 = (const float*)d_in[3];
    const float* b2 = (const float*)d_in[4];
    const int*   ei = (const int*)d_in[5];

    char* ws = (char*)d_ws;
    int*   cnt    = (int*)  (ws + OFF_CNT);
    int*   rowoff = (int*)  (ws + OFF_ROWOFF);
    int*   cursor = (int*)  (ws + OFF_CURSOR);
    float* dinv   = (float*)(ws + OFF_DINV);
    int*   bsum   = (int*)  (ws + OFF_BSUM);
    int*   csr    = (int*)  (ws + OFF_CSR);
    unsigned short* wth = (unsigned short*)(ws + OFF_WTH);
    unsigned short* wtl = (unsigned short*)(ws + OFF_WTL);
    unsigned short* g1b = (unsigned short*)(ws + OFF_G1B);
    float* g2     = (float*)(ws + OFF_G2);
    float* out    = (float*)d_out;

    hipMemsetAsync(cnt, 0, N_NODES * sizeof(int), stream);
    hist_kernel<<<2048, 256, 0, stream>>>(ei, cnt);
    scan_sums<<<NBLK, 256, 0, stream>>>(cnt, bsum);
    scan_top<<<1, 256, 0, stream>>>(bsum);
    scan_write<<<NBLK, 256, 0, stream>>>(cnt, bsum, rowoff, cursor, dinv);
    scatter_kernel<<<2048, 256, 0, stream>>>(ei, cursor, csr);
    wsplit_kernel<<<1024, 256, 0, stream>>>(W1, wth, wtl);

    gemm1_mfma<<<(N_NODES + 31) / 32, 128, 0, stream>>>(x, wth, wtl, dinv, g1b);

    agg1g2_kernel<<<(N_NODES + 3) / 4, 256, 0, stream>>>(g1b, csr, rowoff, cnt, dinv, b1, W2, g2);
    agg2_kernel<<<(N_NODES + 3) / 4, 256, 0, stream>>>(g2, csr, rowoff, cnt, dinv, b2, out);
}

// Round 5
// 469.677 us; speedup vs baseline: 1.4155x; 1.4155x over previous
//
#include <hip/hip_runtime.h>
#include <math.h>

#define N_NODES 50000
#define IN_DIM  1000
#define HIDDEN  256
#define N_EDGES 1600000
#define NBLK    196      // ceil(50000/256)
#define NSTEP   63       // ceil(1000/16)

typedef short bf16x8 __attribute__((ext_vector_type(8)));
typedef float f32x16 __attribute__((ext_vector_type(16)));

__device__ __forceinline__ unsigned short f2bf_rne(float f) {
    unsigned u = __builtin_bit_cast(unsigned, f);
    unsigned r = (u + 0x7FFFu + ((u >> 16) & 1u)) >> 16;
    return (unsigned short)r;
}
__device__ __forceinline__ float bf2f(unsigned short b) {
    unsigned u = ((unsigned)b) << 16;
    return __builtin_bit_cast(float, u);
}
__device__ __forceinline__ unsigned cvt_pk_bf16(float a, float b) {
    unsigned r;
    asm("v_cvt_pk_bf16_f32 %0, %1, %2" : "=v"(r) : "v"(a), "v"(b));
    return r;   // [15:0]=bf16(a), [31:16]=bf16(b)
}

// ---------------- degree histogram ----------------
__global__ void hist_kernel(const int* __restrict__ ei, int* __restrict__ cnt) {
    int e = blockIdx.x * blockDim.x + threadIdx.x;
    int stride = gridDim.x * blockDim.x;
    for (; e < N_EDGES; e += stride) {
        int d = ei[N_EDGES + e];
        if ((unsigned)d < N_NODES) atomicAdd(&cnt[d], 1);
    }
}

// ---------------- 3-phase scan ----------------
__global__ __launch_bounds__(256) void scan_sums(const int* __restrict__ cnt, int* __restrict__ bsum) {
    __shared__ int s[256];
    int t = threadIdx.x;
    int i = blockIdx.x * 256 + t;
    s[t] = (i < N_NODES) ? cnt[i] : 0;
    __syncthreads();
    #pragma unroll
    for (int off = 128; off > 0; off >>= 1) {
        if (t < off) s[t] += s[t + off];
        __syncthreads();
    }
    if (t == 0) bsum[blockIdx.x] = s[0];
}

__global__ __launch_bounds__(256) void scan_top(int* __restrict__ bsum) {
    __shared__ int s[256];
    int t = threadIdx.x;
    int v = (t < NBLK) ? bsum[t] : 0;
    s[t] = v;
    __syncthreads();
    for (int off = 1; off < 256; off <<= 1) {
        int x = (t >= off) ? s[t - off] : 0;
        __syncthreads();
        s[t] += x;
        __syncthreads();
    }
    if (t < NBLK) bsum[t] = s[t] - v;   // exclusive
}

__global__ __launch_bounds__(256) void scan_write(const int* __restrict__ cnt, const int* __restrict__ bsum,
                                                  int* __restrict__ rowoff, int* __restrict__ cursor,
                                                  float* __restrict__ dinv) {
    __shared__ int s[256];
    int t = threadIdx.x;
    int i = blockIdx.x * 256 + t;
    int v = (i < N_NODES) ? cnt[i] : 0;
    s[t] = v;
    __syncthreads();
    for (int off = 1; off < 256; off <<= 1) {
        int x = (t >= off) ? s[t - off] : 0;
        __syncthreads();
        s[t] += x;
        __syncthreads();
    }
    if (i < N_NODES) {
        int ro = bsum[blockIdx.x] + s[t] - v;   // exclusive
        rowoff[i] = ro;
        cursor[i] = ro;
        dinv[i]  = rsqrtf((float)v + 1.0f);
    }
}

// ---------------- counting-sort scatter ----------------
__global__ void scatter_kernel(const int* __restrict__ ei,
                               int* __restrict__ cursor, int* __restrict__ csr) {
    int e = blockIdx.x * blockDim.x + threadIdx.x;
    int stride = gridDim.x * blockDim.x;
    for (; e < N_EDGES; e += stride) {
        int s = ei[e];
        int d = ei[N_EDGES + e];
        if ((unsigned)d < N_NODES && (unsigned)s < N_NODES) {
            int pos = atomicAdd(&cursor[d], 1);
            csr[pos] = s;
        }
    }
}

// ---------------- W1 split + pack into MFMA-fragment order ----------------
// Wp[ci 0..7][step 0..63][plane h/l][lane 0..63][j 0..7]  (bf16)
// element: col = ci*32 + (lane&31), k = step*16 + (lane>>5)*8 + j
__global__ __launch_bounds__(256) void wsplit_kernel(const float* __restrict__ W1,
                                                     unsigned short* __restrict__ Wp) {
    int idx = blockIdx.x * 256 + threadIdx.x;   // 256 cols * 1024 k
    int c = idx >> 10, k = idx & 1023;
    float v = (k < IN_DIM) ? W1[(size_t)k * HIDDEN + c] : 0.0f;
    unsigned short hb = f2bf_rne(v);
    unsigned short lb = f2bf_rne(v - bf2f(hb));
    int ci = c >> 5, lr = c & 31;
    int step = k >> 4, rem = k & 15;
    int lq = rem >> 3, j = rem & 7;
    int lane = lq * 32 + lr;
    size_t base = ((size_t)(ci * 64 + step) * 2 * 64 + lane) * 8 + j;
    Wp[base] = hb;          // plane h
    Wp[base + 512] = lb;    // plane l
}

// ---------------- GEMM1 (MFMA, LDS-staged A, packed coalesced B) ----------------
// Block: 256 thr = 4 waves; tile M=64 x N=256. Wave w: mtile=w>>1 (32 rows),
// n-half = w&1 (128 cols = 4 n-tiles). acc = f32x16[4] (64 VGPR).
__global__ __launch_bounds__(256) void gemm1_mfma(const float* __restrict__ X,
                                                  const unsigned short* __restrict__ Wp,
                                                  const float* __restrict__ dinv,
                                                  unsigned short* __restrict__ G1b) {
    __shared__ unsigned short sA[4096];   // 2 buf x [2 mtile x (h 512 + l 512)] shorts = 8 KB
    const int tid = threadIdx.x;
    const int w   = tid >> 6;
    const int l   = tid & 63;
    const int lr  = l & 31;
    const int lq  = l >> 5;
    const int mtile  = w >> 1;
    const int nibase = (w & 1) * 4;
    const int m0 = blockIdx.x * 64;

    // staging role: thread t loads row sr = t>>2, k-seg ss = t&3 (4 floats)
    const int sr = tid >> 2;
    const int ss = tid & 3;
    const int slq = ss >> 1, shalf = ss & 1;
    const int slane = slq * 32 + (sr & 31);
    const int sbase = (sr >> 5) * 1024 + slane * 8 + shalf * 4;   // shorts (h); l at +512

    int rg = m0 + sr;
    const float* ap = X + (size_t)(rg < N_NODES ? rg : N_NODES - 1) * IN_DIM + ss * 4;

    f32x16 acc[4] = {};

    // prologue: stage step 0 into buf 0  (k = ss*4 <= 12, always valid)
    {
        float4 f = *(const float4*)ap;
        unsigned h0 = cvt_pk_bf16(f.x, f.y);
        unsigned h1 = cvt_pk_bf16(f.z, f.w);
        float hx = __builtin_bit_cast(float, h0 << 16);
        float hy = __builtin_bit_cast(float, h0 & 0xFFFF0000u);
        float hz = __builtin_bit_cast(float, h1 << 16);
        float hw = __builtin_bit_cast(float, h1 & 0xFFFF0000u);
        unsigned l0 = cvt_pk_bf16(f.x - hx, f.y - hy);
        unsigned l1 = cvt_pk_bf16(f.z - hz, f.w - hw);
        *(uint2*)(sA + sbase)       = make_uint2(h0, h1);
        *(uint2*)(sA + sbase + 512) = make_uint2(l0, l1);
    }
    __syncthreads();

    int cur = 0;
    #pragma unroll 1
    for (int step = 0; step < NSTEP; ++step) {
        const int nxt = step + 1;
        // prefetch next A tile (global, coalesced)
        float4 fn = make_float4(0.f, 0.f, 0.f, 0.f);
        if (nxt < NSTEP) {
            int k = nxt * 16 + ss * 4;
            if (k < IN_DIM) fn = *(const float4*)(ap + nxt * 16);
        }
        // B fragments: coalesced 1 KB wave-reads from packed W (L2-resident)
        const unsigned short* bp = Wp + (size_t)((nibase * 64 + step) * 2) * 512 + l * 8;
        bf16x8 bh[4], bl[4];
        #pragma unroll
        for (int ni = 0; ni < 4; ++ni) {
            bh[ni] = *(const bf16x8*)(bp + (size_t)ni * 65536);
            bl[ni] = *(const bf16x8*)(bp + (size_t)ni * 65536 + 512);
        }
        // A fragments from LDS (fragment-linear: lane's 16 B contiguous, conflict-free)
        const unsigned short* ab = sA + cur * 2048 + mtile * 1024;
        bf16x8 ah = *(const bf16x8*)(ab + l * 8);
        bf16x8 al = *(const bf16x8*)(ab + 512 + l * 8);

        #pragma unroll
        for (int ni = 0; ni < 4; ++ni) {
            acc[ni] = __builtin_amdgcn_mfma_f32_32x32x16_bf16(ah, bh[ni], acc[ni], 0, 0, 0);
            acc[ni] = __builtin_amdgcn_mfma_f32_32x32x16_bf16(ah, bl[ni], acc[ni], 0, 0, 0);
            acc[ni] = __builtin_amdgcn_mfma_f32_32x32x16_bf16(al, bh[ni], acc[ni], 0, 0, 0);
        }

        // convert + write next tile into the other buffer
        if (nxt < NSTEP) {
            unsigned h0 = cvt_pk_bf16(fn.x, fn.y);
            unsigned h1 = cvt_pk_bf16(fn.z, fn.w);
            float hx = __builtin_bit_cast(float, h0 << 16);
            float hy = __builtin_bit_cast(float, h0 & 0xFFFF0000u);
            float hz = __builtin_bit_cast(float, h1 << 16);
            float hw = __builtin_bit_cast(float, h1 & 0xFFFF0000u);
            unsigned l0 = cvt_pk_bf16(fn.x - hx, fn.y - hy);
            unsigned l1 = cvt_pk_bf16(fn.z - hz, fn.w - hw);
            unsigned short* wb = sA + (cur ^ 1) * 2048;
            *(uint2*)(wb + sbase)       = make_uint2(h0, h1);
            *(uint2*)(wb + sbase + 512) = make_uint2(l0, l1);
        }
        __syncthreads();
        cur ^= 1;
    }

    // epilogue: C/D layout col=lane&31, row=(r&3)+8*(r>>2)+4*(lane>>5)
    #pragma unroll
    for (int r = 0; r < 16; ++r) {
        int row = m0 + mtile * 32 + (r & 3) + 8 * (r >> 2) + 4 * lq;
        if (row >= N_NODES) continue;
        float dv = dinv[row];
        #pragma unroll
        for (int ni = 0; ni < 4; ++ni) {
            int col = nibase * 32 + ni * 32 + lr;
            G1b[(size_t)row * HIDDEN + col] = f2bf_rne(dv * acc[ni][r]);
        }
    }
}

// ---------------- fused agg1 + gemm2 ----------------
__global__ __launch_bounds__(256) void agg1g2_kernel(const unsigned short* __restrict__ G,
                                                     const int* __restrict__ csr,
                                                     const int* __restrict__ rowoff,
                                                     const int* __restrict__ cnt,
                                                     const float* __restrict__ dinv,
                                                     const float* __restrict__ b1,
                                                     const float* __restrict__ W2,
                                                     float* __restrict__ G2) {
    __shared__ float2 wl[HIDDEN];
    int tid = threadIdx.x;
    wl[tid] = make_float2(W2[tid * 2], W2[tid * 2 + 1]);
    __syncthreads();
    int wave = tid >> 6;
    int lane = tid & 63;
    int d = blockIdx.x * 4 + wave;
    if (d >= N_NODES) return;
    int c0 = lane * 4;
    ushort4 sv = *(const ushort4*)&G[(size_t)d * HIDDEN + c0];
    float ax = bf2f(sv.x), ay = bf2f(sv.y), az = bf2f(sv.z), aw = bf2f(sv.w);
    int beg = rowoff[d], num = cnt[d];
    int end = beg + num;
    int e = beg;
    // 4-way unroll for memory-level parallelism (add order preserved)
    for (; e + 4 <= end; e += 4) {
        int s0 = csr[e], s1 = csr[e + 1], s2 = csr[e + 2], s3 = csr[e + 3];
        ushort4 v0 = *(const ushort4*)&G[(size_t)s0 * HIDDEN + c0];
        ushort4 v1 = *(const ushort4*)&G[(size_t)s1 * HIDDEN + c0];
        ushort4 v2 = *(const ushort4*)&G[(size_t)s2 * HIDDEN + c0];
        ushort4 v3 = *(const ushort4*)&G[(size_t)s3 * HIDDEN + c0];
        ax += bf2f(v0.x); ay += bf2f(v0.y); az += bf2f(v0.z); aw += bf2f(v0.w);
        ax += bf2f(v1.x); ay += bf2f(v1.y); az += bf2f(v1.z); aw += bf2f(v1.w);
        ax += bf2f(v2.x); ay += bf2f(v2.y); az += bf2f(v2.z); aw += bf2f(v2.w);
        ax += bf2f(v3.x); ay += bf2f(v3.y); az += bf2f(v3.z); aw += bf2f(v3.w);
    }
    for (; e < end; ++e) {
        int s = csr[e];
        ushort4 v = *(const ushort4*)&G[(size_t)s * HIDDEN + c0];
        ax += bf2f(v.x); ay += bf2f(v.y); az += bf2f(v.z); aw += bf2f(v.w);
    }
    float dv = dinv[d];
    float4 bb = *(const float4*)&b1[c0];
    float zx = fmaxf(dv * ax + bb.x, 0.f);
    float zy = fmaxf(dv * ay + bb.y, 0.f);
    float zz = fmaxf(dv * az + bb.z, 0.f);
    float zw = fmaxf(dv * aw + bb.w, 0.f);
    float2 w0 = wl[c0], w1 = wl[c0 + 1], w2_ = wl[c0 + 2], w3 = wl[c0 + 3];
    float a0 = zx * w0.x + zy * w1.x + zz * w2_.x + zw * w3.x;
    float a1 = zx * w0.y + zy * w1.y + zz * w2_.y + zw * w3.y;
    #pragma unroll
    for (int off = 32; off; off >>= 1) {
        a0 += __shfl_xor(a0, off, 64);
        a1 += __shfl_xor(a1, off, 64);
    }
    if (lane == 0) {
        G2[d * 2 + 0] = dv * a0;
        G2[d * 2 + 1] = dv * a1;
    }
}

// ---------------- agg2 ----------------
__global__ __launch_bounds__(256) void agg2_kernel(const float* __restrict__ G2,
                                                   const int* __restrict__ csr,
                                                   const int* __restrict__ rowoff,
                                                   const int* __restrict__ cnt,
                                                   const float* __restrict__ dinv,
                                                   const float* __restrict__ b2,
                                                   float* __restrict__ out) {
    int wave = threadIdx.x >> 6, lane = threadIdx.x & 63;
    int d = blockIdx.x * 4 + wave;
    if (d >= N_NODES) return;
    int beg = rowoff[d], num = cnt[d];
    float a0 = 0.f, a1 = 0.f;
    for (int e = lane; e < num; e += 64) {
        int s = csr[beg + e];
        float2 g = *(const float2*)&G2[s * 2];
        a0 += g.x; a1 += g.y;
    }
    #pragma unroll
    for (int off = 32; off; off >>= 1) {
        a0 += __shfl_xor(a0, off, 64);
        a1 += __shfl_xor(a1, off, 64);
    }
    if (lane == 0) {
        float2 self = *(const float2*)&G2[d * 2];
        float dv = dinv[d];
        out[d * 2 + 0] = dv * (a0 + self.x) + b2[0];
        out[d * 2 + 1] = dv * (a1 + self.y) + b2[1];
    }
}

// ---------------- workspace layout (bytes) ----------------
#define OFF_CNT     0u
#define OFF_ROWOFF  262144u
#define OFF_CURSOR  524288u
#define OFF_DINV    786432u
#define OFF_BSUM    1048576u
#define OFF_CSR     1310720u
#define OFF_WP      8388608u     // 1 MB packed (h+l)
#define OFF_G1B     9437184u
#define OFF_G2      35651584u
// total ~36.1 MB

extern "C" void kernel_launch(void* const* d_in, const int* in_sizes, int n_in,
                              void* d_out, int out_size, void* d_ws, size_t ws_size,
                              hipStream_t stream) {
    const float* x  = (const float*)d_in[0];
    const float* W1 = (const float*)d_in[1];
    const float* b1 = (const float*)d_in[2];
    const float* W2 = (const float*)d_in[3];
    const float* b2 = (const float*)d_in[4];
    const int*   ei = (const int*)d_in[5];

    char* ws = (char*)d_ws;
    int*   cnt    = (int*)  (ws + OFF_CNT);
    int*   rowoff = (int*)  (ws + OFF_ROWOFF);
    int*   cursor = (int*)  (ws + OFF_CURSOR);
    float* dinv   = (float*)(ws + OFF_DINV);
    int*   bsum   = (int*)  (ws + OFF_BSUM);
    int*   csr    = (int*)  (ws + OFF_CSR);
    unsigned short* wp  = (unsigned short*)(ws + OFF_WP);
    unsigned short* g1b = (unsigned short*)(ws + OFF_G1B);
    float* g2     = (float*)(ws + OFF_G2);
    float* out    = (float*)d_out;

    hipMemsetAsync(cnt, 0, N_NODES * sizeof(int), stream);
    hist_kernel<<<2048, 256, 0, stream>>>(ei, cnt);
    scan_sums<<<NBLK, 256, 0, stream>>>(cnt, bsum);
    scan_top<<<1, 256, 0, stream>>>(bsum);
    scan_write<<<NBLK, 256, 0, stream>>>(cnt, bsum, rowoff, cursor, dinv);
    scatter_kernel<<<2048, 256, 0, stream>>>(ei, cursor, csr);
    wsplit_kernel<<<1024, 256, 0, stream>>>(W1, wp);

    gemm1_mfma<<<(N_NODES + 63) / 64, 256, 0, stream>>>(x, wp, dinv, g1b);

    agg1g2_kernel<<<(N_NODES + 3) / 4, 256, 0, stream>>>(g1b, csr, rowoff, cnt, dinv, b1, W2, g2);
    agg2_kernel<<<(N_NODES + 3) / 4, 256, 0, stream>>>(g2, csr, rowoff, cnt, dinv, b2, out);
}

// Round 6
// 468.564 us; speedup vs baseline: 1.4188x; 1.0024x over previous
//
#include <hip/hip_runtime.h>
#include <math.h>

#define N_NODES 50000
#define IN_DIM  1000
#define HIDDEN  256
#define N_EDGES 1600000
#define NBLK    196      // ceil(50000/256)
#define NSTEP   63       // ceil(1000/16)

typedef short bf16x8 __attribute__((ext_vector_type(8)));
typedef float f32x16 __attribute__((ext_vector_type(16)));

__device__ __forceinline__ unsigned short f2bf_rne(float f) {
    unsigned u = __builtin_bit_cast(unsigned, f);
    unsigned r = (u + 0x7FFFu + ((u >> 16) & 1u)) >> 16;
    return (unsigned short)r;
}
__device__ __forceinline__ float bf2f(unsigned short b) {
    unsigned u = ((unsigned)b) << 16;
    return __builtin_bit_cast(float, u);
}
__device__ __forceinline__ unsigned cvt_pk_bf16(float a, float b) {
    unsigned r;
    asm("v_cvt_pk_bf16_f32 %0, %1, %2" : "=v"(r) : "v"(a), "v"(b));
    return r;   // [15:0]=bf16(a), [31:16]=bf16(b)
}
#define GLOAD_LDS16(gp, lp) \
    __builtin_amdgcn_global_load_lds((const __attribute__((address_space(1))) unsigned*)(gp), \
                                     (__attribute__((address_space(3))) unsigned*)(lp), 16, 0, 0)

// ---------------- degree histogram ----------------
__global__ void hist_kernel(const int* __restrict__ ei, int* __restrict__ cnt) {
    int e = blockIdx.x * blockDim.x + threadIdx.x;
    int stride = gridDim.x * blockDim.x;
    for (; e < N_EDGES; e += stride) {
        int d = ei[N_EDGES + e];
        if ((unsigned)d < N_NODES) atomicAdd(&cnt[d], 1);
    }
}

// ---------------- 3-phase scan ----------------
__global__ __launch_bounds__(256) void scan_sums(const int* __restrict__ cnt, int* __restrict__ bsum) {
    __shared__ int s[256];
    int t = threadIdx.x;
    int i = blockIdx.x * 256 + t;
    s[t] = (i < N_NODES) ? cnt[i] : 0;
    __syncthreads();
    #pragma unroll
    for (int off = 128; off > 0; off >>= 1) {
        if (t < off) s[t] += s[t + off];
        __syncthreads();
    }
    if (t == 0) bsum[blockIdx.x] = s[0];
}

__global__ __launch_bounds__(256) void scan_top(int* __restrict__ bsum) {
    __shared__ int s[256];
    int t = threadIdx.x;
    int v = (t < NBLK) ? bsum[t] : 0;
    s[t] = v;
    __syncthreads();
    for (int off = 1; off < 256; off <<= 1) {
        int x = (t >= off) ? s[t - off] : 0;
        __syncthreads();
        s[t] += x;
        __syncthreads();
    }
    if (t < NBLK) bsum[t] = s[t] - v;   // exclusive
}

__global__ __launch_bounds__(256) void scan_write(const int* __restrict__ cnt, const int* __restrict__ bsum,
                                                  int* __restrict__ rowoff, int* __restrict__ cursor,
                                                  float* __restrict__ dinv) {
    __shared__ int s[256];
    int t = threadIdx.x;
    int i = blockIdx.x * 256 + t;
    int v = (i < N_NODES) ? cnt[i] : 0;
    s[t] = v;
    __syncthreads();
    for (int off = 1; off < 256; off <<= 1) {
        int x = (t >= off) ? s[t - off] : 0;
        __syncthreads();
        s[t] += x;
        __syncthreads();
    }
    if (i < N_NODES) {
        int ro = bsum[blockIdx.x] + s[t] - v;   // exclusive
        rowoff[i] = ro;
        cursor[i] = ro;
        dinv[i]  = rsqrtf((float)v + 1.0f);
    }
}

// ---------------- counting-sort scatter ----------------
__global__ void scatter_kernel(const int* __restrict__ ei,
                               int* __restrict__ cursor, int* __restrict__ csr) {
    int e = blockIdx.x * blockDim.x + threadIdx.x;
    int stride = gridDim.x * blockDim.x;
    for (; e < N_EDGES; e += stride) {
        int s = ei[e];
        int d = ei[N_EDGES + e];
        if ((unsigned)d < N_NODES && (unsigned)s < N_NODES) {
            int pos = atomicAdd(&cursor[d], 1);
            csr[pos] = s;
        }
    }
}

// ---------------- W1 split + pack per-step fragment blocks ----------------
// Wp2[step 0..63][ci 0..7][pl 0..1][lane 0..63][j 0..7] (bf16), 16 KB per step.
// element: col = ci*32 + (lane&31), k = step*16 + (lane>>5)*8 + j
__global__ __launch_bounds__(256) void wsplit_kernel(const float* __restrict__ W1,
                                                     unsigned short* __restrict__ Wp) {
    int idx = blockIdx.x * 256 + threadIdx.x;   // 256 cols * 1024 k
    int c = idx >> 10, k = idx & 1023;
    float v = (k < IN_DIM) ? W1[(size_t)k * HIDDEN + c] : 0.0f;
    unsigned short hb = f2bf_rne(v);
    unsigned short lb = f2bf_rne(v - bf2f(hb));
    int ci = c >> 5;
    int step = k >> 4, kk = k & 15;
    int lane = (kk >> 3) * 32 + (c & 31);
    int j = kk & 7;
    size_t base = ((size_t)((step * 8 + ci) * 2) * 64 + lane) * 8 + j;
    Wp[base] = hb;          // plane h
    Wp[base + 512] = lb;    // plane l
}

// ---------------- GEMM1: 256x256 tile, 8 waves, A+B in LDS, 2-phase pipeline ----------------
// wave w: rows R*64 (R=w>>1), cols C*128 (C=w&1); per wave 24 MFMA/step.
__global__ __launch_bounds__(512) void gemm1_mfma(const float* __restrict__ X,
                                                  const unsigned short* __restrict__ Wp,
                                                  const float* __restrict__ dinv,
                                                  unsigned short* __restrict__ G1b) {
    __shared__ unsigned short sA[2][8192];   // [mtile 8][pl 2][lane 64][8] bf16, 16KB per buf
    __shared__ unsigned short sB[2][8192];   // [ci 8][pl 2][lane 64][8]   bf16, 16KB per buf
    const int tid = threadIdx.x;
    const int w   = tid >> 6;
    const int l   = tid & 63;
    const int lr  = l & 31;
    const int lq  = l >> 5;
    const int R   = w >> 1;        // 0..3
    const int C   = w & 1;         // 0..1
    const int m0  = blockIdx.x * 256;

    // A staging role: thread t -> row rl = t>>1, k-half kh = t&1 (8 floats)
    const int rl = tid >> 1;
    const int kh = tid & 1;
    const int smt = rl >> 5;                      // mtile
    const int slane = kh * 32 + (rl & 31);
    const int sidx_h = (smt * 2 + 0) * 512 + slane * 8;   // shorts
    int rg = m0 + rl;
    const float* ap = X + (size_t)(rg < N_NODES ? rg : N_NODES - 1) * IN_DIM + kh * 8;

    // B staging role: wave w stages chunks w*2, w*2+1 (1KB each)
    const unsigned short* bsrc = Wp + (size_t)(w * 2) * 512 + l * 8;

    f32x16 acc[2][4] = {};

    // ---- helper lambdas (inlined) ----
    auto stageA = [&](int s, int buf) {
        int k = s * 16 + kh * 8;
        float4 f0 = make_float4(0.f,0.f,0.f,0.f), f1 = f0;
        if (k <= IN_DIM - 8) {
            f0 = *(const float4*)(ap + (size_t)s * 16);
            f1 = *(const float4*)(ap + (size_t)s * 16 + 4);
        }
        unsigned h0 = cvt_pk_bf16(f0.x, f0.y);
        unsigned h1 = cvt_pk_bf16(f0.z, f0.w);
        unsigned h2 = cvt_pk_bf16(f1.x, f1.y);
        unsigned h3 = cvt_pk_bf16(f1.z, f1.w);
        unsigned l0 = cvt_pk_bf16(f0.x - __builtin_bit_cast(float, h0 << 16),
                                  f0.y - __builtin_bit_cast(float, h0 & 0xFFFF0000u));
        unsigned l1 = cvt_pk_bf16(f0.z - __builtin_bit_cast(float, h1 << 16),
                                  f0.w - __builtin_bit_cast(float, h1 & 0xFFFF0000u));
        unsigned l2 = cvt_pk_bf16(f1.x - __builtin_bit_cast(float, h2 << 16),
                                  f1.y - __builtin_bit_cast(float, h2 & 0xFFFF0000u));
        unsigned l3 = cvt_pk_bf16(f1.z - __builtin_bit_cast(float, h3 << 16),
                                  f1.w - __builtin_bit_cast(float, h3 & 0xFFFF0000u));
        *(uint4*)&sA[buf][sidx_h]       = make_uint4(h0, h1, h2, h3);
        *(uint4*)&sA[buf][sidx_h + 512] = make_uint4(l0, l1, l2, l3);
    };
    auto stageB = [&](int s, int buf) {
        const unsigned short* src = bsrc + (size_t)s * 8192;
        GLOAD_LDS16(src,        &sB[buf][(w * 2) * 512]);
        GLOAD_LDS16(src + 512,  &sB[buf][(w * 2 + 1) * 512]);
    };

    // prologue: stage step 0 into buf 0
    stageB(0, 0);
    stageA(0, 0);
    __syncthreads();

    #pragma unroll 1
    for (int s = 0; s < NSTEP; ++s) {
        const int buf = s & 1;
        // issue next-step staging loads first (latency hides under MFMA)
        if (s + 1 < NSTEP) stageB(s + 1, buf ^ 1);
        float4 f0 = make_float4(0.f,0.f,0.f,0.f), f1 = f0;
        if (s + 1 < NSTEP) {
            int k = (s + 1) * 16 + kh * 8;
            if (k <= IN_DIM - 8) {
                f0 = *(const float4*)(ap + (size_t)(s + 1) * 16);
                f1 = *(const float4*)(ap + (size_t)(s + 1) * 16 + 4);
            }
        }

        // fragments from LDS
        bf16x8 ah[2], al[2], bh[4], bl[4];
        #pragma unroll
        for (int mi = 0; mi < 2; ++mi) {
            int mt = R * 2 + mi;
            ah[mi] = *(const bf16x8*)&sA[buf][(mt * 2 + 0) * 512 + l * 8];
            al[mi] = *(const bf16x8*)&sA[buf][(mt * 2 + 1) * 512 + l * 8];
        }
        #pragma unroll
        for (int ni = 0; ni < 4; ++ni) {
            int ci = C * 4 + ni;
            bh[ni] = *(const bf16x8*)&sB[buf][(ci * 2 + 0) * 512 + l * 8];
            bl[ni] = *(const bf16x8*)&sB[buf][(ci * 2 + 1) * 512 + l * 8];
        }
        #pragma unroll
        for (int mi = 0; mi < 2; ++mi)
            #pragma unroll
            for (int ni = 0; ni < 4; ++ni) {
                acc[mi][ni] = __builtin_amdgcn_mfma_f32_32x32x16_bf16(ah[mi], bh[ni], acc[mi][ni], 0, 0, 0);
                acc[mi][ni] = __builtin_amdgcn_mfma_f32_32x32x16_bf16(ah[mi], bl[ni], acc[mi][ni], 0, 0, 0);
                acc[mi][ni] = __builtin_amdgcn_mfma_f32_32x32x16_bf16(al[mi], bh[ni], acc[mi][ni], 0, 0, 0);
            }

        // convert + ds_write next A tile into the other buffer
        if (s + 1 < NSTEP) {
            unsigned h0 = cvt_pk_bf16(f0.x, f0.y);
            unsigned h1 = cvt_pk_bf16(f0.z, f0.w);
            unsigned h2 = cvt_pk_bf16(f1.x, f1.y);
            unsigned h3 = cvt_pk_bf16(f1.z, f1.w);
            unsigned l0 = cvt_pk_bf16(f0.x - __builtin_bit_cast(float, h0 << 16),
                                      f0.y - __builtin_bit_cast(float, h0 & 0xFFFF0000u));
            unsigned l1 = cvt_pk_bf16(f0.z - __builtin_bit_cast(float, h1 << 16),
                                      f0.w - __builtin_bit_cast(float, h1 & 0xFFFF0000u));
            unsigned l2 = cvt_pk_bf16(f1.x - __builtin_bit_cast(float, h2 << 16),
                                      f1.y - __builtin_bit_cast(float, h2 & 0xFFFF0000u));
            unsigned l3 = cvt_pk_bf16(f1.z - __builtin_bit_cast(float, h3 << 16),
                                      f1.w - __builtin_bit_cast(float, h3 & 0xFFFF0000u));
            *(uint4*)&sA[buf ^ 1][sidx_h]       = make_uint4(h0, h1, h2, h3);
            *(uint4*)&sA[buf ^ 1][sidx_h + 512] = make_uint4(l0, l1, l2, l3);
        }
        __syncthreads();   // compiler drains vmcnt (global_load_lds) + lgkmcnt here
    }

    // epilogue: C/D layout col=lane&31, row=(r&3)+8*(r>>2)+4*(lane>>5)
    #pragma unroll
    for (int mi = 0; mi < 2; ++mi)
        #pragma unroll
        for (int r = 0; r < 16; ++r) {
            int row = m0 + R * 64 + mi * 32 + (r & 3) + 8 * (r >> 2) + 4 * lq;
            if (row >= N_NODES) continue;
            float dv = dinv[row];
            #pragma unroll
            for (int ni = 0; ni < 4; ++ni) {
                int col = C * 128 + ni * 32 + lr;
                G1b[(size_t)row * HIDDEN + col] = f2bf_rne(dv * acc[mi][ni][r]);
            }
        }
}

// ---------------- fused agg1 + gemm2 ----------------
__global__ __launch_bounds__(256) void agg1g2_kernel(const unsigned short* __restrict__ G,
                                                     const int* __restrict__ csr,
                                                     const int* __restrict__ rowoff,
                                                     const int* __restrict__ cnt,
                                                     const float* __restrict__ dinv,
                                                     const float* __restrict__ b1,
                                                     const float* __restrict__ W2,
                                                     float* __restrict__ G2) {
    __shared__ float2 wl[HIDDEN];
    int tid = threadIdx.x;
    wl[tid] = make_float2(W2[tid * 2], W2[tid * 2 + 1]);
    __syncthreads();
    int wave = tid >> 6;
    int lane = tid & 63;
    int d = blockIdx.x * 4 + wave;
    if (d >= N_NODES) return;
    int c0 = lane * 4;
    ushort4 sv = *(const ushort4*)&G[(size_t)d * HIDDEN + c0];
    float ax = bf2f(sv.x), ay = bf2f(sv.y), az = bf2f(sv.z), aw = bf2f(sv.w);
    int beg = rowoff[d], num = cnt[d];
    int end = beg + num;
    int e = beg;
    for (; e + 4 <= end; e += 4) {
        int s0 = csr[e], s1 = csr[e + 1], s2 = csr[e + 2], s3 = csr[e + 3];
        ushort4 v0 = *(const ushort4*)&G[(size_t)s0 * HIDDEN + c0];
        ushort4 v1 = *(const ushort4*)&G[(size_t)s1 * HIDDEN + c0];
        ushort4 v2 = *(const ushort4*)&G[(size_t)s2 * HIDDEN + c0];
        ushort4 v3 = *(const ushort4*)&G[(size_t)s3 * HIDDEN + c0];
        ax += bf2f(v0.x); ay += bf2f(v0.y); az += bf2f(v0.z); aw += bf2f(v0.w);
        ax += bf2f(v1.x); ay += bf2f(v1.y); az += bf2f(v1.z); aw += bf2f(v1.w);
        ax += bf2f(v2.x); ay += bf2f(v2.y); az += bf2f(v2.z); aw += bf2f(v2.w);
        ax += bf2f(v3.x); ay += bf2f(v3.y); az += bf2f(v3.z); aw += bf2f(v3.w);
    }
    for (; e < end; ++e) {
        int s = csr[e];
        ushort4 v = *(const ushort4*)&G[(size_t)s * HIDDEN + c0];
        ax += bf2f(v.x); ay += bf2f(v.y); az += bf2f(v.z); aw += bf2f(v.w);
    }
    float dv = dinv[d];
    float4 bb = *(const float4*)&b1[c0];
    float zx = fmaxf(dv * ax + bb.x, 0.f);
    float zy = fmaxf(dv * ay + bb.y, 0.f);
    float zz = fmaxf(dv * az + bb.z, 0.f);
    float zw = fmaxf(dv * aw + bb.w, 0.f);
    float2 w0 = wl[c0], w1 = wl[c0 + 1], w2_ = wl[c0 + 2], w3 = wl[c0 + 3];
    float a0 = zx * w0.x + zy * w1.x + zz * w2_.x + zw * w3.x;
    float a1 = zx * w0.y + zy * w1.y + zz * w2_.y + zw * w3.y;
    #pragma unroll
    for (int off = 32; off; off >>= 1) {
        a0 += __shfl_xor(a0, off, 64);
        a1 += __shfl_xor(a1, off, 64);
    }
    if (lane == 0) {
        G2[d * 2 + 0] = dv * a0;
        G2[d * 2 + 1] = dv * a1;
    }
}

// ---------------- agg2 ----------------
__global__ __launch_bounds__(256) void agg2_kernel(const float* __restrict__ G2,
                                                   const int* __restrict__ csr,
                                                   const int* __restrict__ rowoff,
                                                   const int* __restrict__ cnt,
                                                   const float* __restrict__ dinv,
                                                   const float* __restrict__ b2,
                                                   float* __restrict__ out) {
    int wave = threadIdx.x >> 6, lane = threadIdx.x & 63;
    int d = blockIdx.x * 4 + wave;
    if (d >= N_NODES) return;
    int beg = rowoff[d], num = cnt[d];
    float a0 = 0.f, a1 = 0.f;
    for (int e = lane; e < num; e += 64) {
        int s = csr[beg + e];
        float2 g = *(const float2*)&G2[s * 2];
        a0 += g.x; a1 += g.y;
    }
    #pragma unroll
    for (int off = 32; off; off >>= 1) {
        a0 += __shfl_xor(a0, off, 64);
        a1 += __shfl_xor(a1, off, 64);
    }
    if (lane == 0) {
        float2 self = *(const float2*)&G2[d * 2];
        float dv = dinv[d];
        out[d * 2 + 0] = dv * (a0 + self.x) + b2[0];
        out[d * 2 + 1] = dv * (a1 + self.y) + b2[1];
    }
}

// ---------------- workspace layout (bytes) ----------------
#define OFF_CNT     0u
#define OFF_ROWOFF  262144u
#define OFF_CURSOR  524288u
#define OFF_DINV    786432u
#define OFF_BSUM    1048576u
#define OFF_CSR     1310720u
#define OFF_WP      8388608u     // 1 MB packed per-step (h+l)
#define OFF_G1B     9437184u
#define OFF_G2      35651584u
// total ~36.1 MB

extern "C" void kernel_launch(void* const* d_in, const int* in_sizes, int n_in,
                              void* d_out, int out_size, void* d_ws, size_t ws_size,
                              hipStream_t stream) {
    const float* x  = (const float*)d_in[0];
    const float* W1 = (const float*)d_in[1];
    const float* b1 = (const float*)d_in[2];
    const float* W2 = (const float*)d_in[3];
    const float* b2 = (const float*)d_in[4];
    const int*   ei = (const int*)d_in[5];

    char* ws = (char*)d_ws;
    int*   cnt    = (int*)  (ws + OFF_CNT);
    int*   rowoff = (int*)  (ws + OFF_ROWOFF);
    int*   cursor = (int*)  (ws + OFF_CURSOR);
    float* dinv   = (float*)(ws + OFF_DINV);
    int*   bsum   = (int*)  (ws + OFF_BSUM);
    int*   csr    = (int*)  (ws + OFF_CSR);
    unsigned short* wp  = (unsigned short*)(ws + OFF_WP);
    unsigned short* g1b = (unsigned short*)(ws + OFF_G1B);
    float* g2     = (float*)(ws + OFF_G2);
    float* out    = (float*)d_out;

    hipMemsetAsync(cnt, 0, N_NODES * sizeof(int), stream);
    hist_kernel<<<2048, 256, 0, stream>>>(ei, cnt);
    scan_sums<<<NBLK, 256, 0, stream>>>(cnt, bsum);
    scan_top<<<1, 256, 0, stream>>>(bsum);
    scan_write<<<NBLK, 256, 0, stream>>>(cnt, bsum, rowoff, cursor, dinv);
    scatter_kernel<<<2048, 256, 0, stream>>>(ei, cursor, csr);
    wsplit_kernel<<<1024, 256, 0, stream>>>(W1, wp);

    gemm1_mfma<<<(N_NODES + 255) / 256, 512, 0, stream>>>(x, wp, dinv, g1b);

    agg1g2_kernel<<<(N_NODES + 3) / 4, 256, 0, stream>>>(g1b, csr, rowoff, cnt, dinv, b1, W2, g2);
    agg2_kernel<<<(N_NODES + 3) / 4, 256, 0, stream>>>(g2, csr, rowoff, cnt, dinv, b2, out);
}

// Round 7
// 435.517 us; speedup vs baseline: 1.5265x; 1.0759x over previous
//
#include <hip/hip_runtime.h>
#include <math.h>

#define N_NODES 50000
#define IN_DIM  1000
#define HIDDEN  256
#define N_EDGES 1600000
#define NBLK    196      // ceil(50000/256)
#define NSTEP   63       // ceil(1000/16)

typedef short bf16x8 __attribute__((ext_vector_type(8)));
typedef float f32x16 __attribute__((ext_vector_type(16)));

__device__ __forceinline__ unsigned short f2bf_rne(float f) {
    unsigned u = __builtin_bit_cast(unsigned, f);
    unsigned r = (u + 0x7FFFu + ((u >> 16) & 1u)) >> 16;
    return (unsigned short)r;
}
__device__ __forceinline__ float bf2f(unsigned short b) {
    unsigned u = ((unsigned)b) << 16;
    return __builtin_bit_cast(float, u);
}
__device__ __forceinline__ unsigned cvt_pk_bf16(float a, float b) {
    unsigned r;
    asm("v_cvt_pk_bf16_f32 %0, %1, %2" : "=v"(r) : "v"(a), "v"(b));
    return r;   // [15:0]=bf16(a), [31:16]=bf16(b)
}
#define GLOAD_LDS16(gp, lp) \
    __builtin_amdgcn_global_load_lds((const __attribute__((address_space(1))) unsigned*)(gp), \
                                     (__attribute__((address_space(3))) unsigned*)(lp), 16, 0, 0)

// ---------------- degree histogram ----------------
__global__ void hist_kernel(const int* __restrict__ ei, int* __restrict__ cnt) {
    int e = blockIdx.x * blockDim.x + threadIdx.x;
    int stride = gridDim.x * blockDim.x;
    for (; e < N_EDGES; e += stride) {
        int d = ei[N_EDGES + e];
        if ((unsigned)d < N_NODES) atomicAdd(&cnt[d], 1);
    }
}

// ---------------- 3-phase scan ----------------
__global__ __launch_bounds__(256) void scan_sums(const int* __restrict__ cnt, int* __restrict__ bsum) {
    __shared__ int s[256];
    int t = threadIdx.x;
    int i = blockIdx.x * 256 + t;
    s[t] = (i < N_NODES) ? cnt[i] : 0;
    __syncthreads();
    #pragma unroll
    for (int off = 128; off > 0; off >>= 1) {
        if (t < off) s[t] += s[t + off];
        __syncthreads();
    }
    if (t == 0) bsum[blockIdx.x] = s[0];
}

__global__ __launch_bounds__(256) void scan_top(int* __restrict__ bsum) {
    __shared__ int s[256];
    int t = threadIdx.x;
    int v = (t < NBLK) ? bsum[t] : 0;
    s[t] = v;
    __syncthreads();
    for (int off = 1; off < 256; off <<= 1) {
        int x = (t >= off) ? s[t - off] : 0;
        __syncthreads();
        s[t] += x;
        __syncthreads();
    }
    if (t < NBLK) bsum[t] = s[t] - v;   // exclusive
}

__global__ __launch_bounds__(256) void scan_write(const int* __restrict__ cnt, const int* __restrict__ bsum,
                                                  int* __restrict__ rowoff, int* __restrict__ cursor,
                                                  float* __restrict__ dinv) {
    __shared__ int s[256];
    int t = threadIdx.x;
    int i = blockIdx.x * 256 + t;
    int v = (i < N_NODES) ? cnt[i] : 0;
    s[t] = v;
    __syncthreads();
    for (int off = 1; off < 256; off <<= 1) {
        int x = (t >= off) ? s[t - off] : 0;
        __syncthreads();
        s[t] += x;
        __syncthreads();
    }
    if (i < N_NODES) {
        int ro = bsum[blockIdx.x] + s[t] - v;   // exclusive
        rowoff[i] = ro;
        cursor[i] = ro;
        dinv[i]  = rsqrtf((float)v + 1.0f);
    }
}

// ---------------- counting-sort scatter ----------------
__global__ void scatter_kernel(const int* __restrict__ ei,
                               int* __restrict__ cursor, int* __restrict__ csr) {
    int e = blockIdx.x * blockDim.x + threadIdx.x;
    int stride = gridDim.x * blockDim.x;
    for (; e < N_EDGES; e += stride) {
        int s = ei[e];
        int d = ei[N_EDGES + e];
        if ((unsigned)d < N_NODES && (unsigned)s < N_NODES) {
            int pos = atomicAdd(&cursor[d], 1);
            csr[pos] = s;
        }
    }
}

// ---------------- W1 split + pack per-step fragment blocks ----------------
// Wp[step 0..63][ci 0..7][pl 0..1][lane 0..63][j 0..7] (bf16), 16 KB per step.
// element: col = ci*32 + (lane&31), k = step*16 + (lane>>5)*8 + j
__global__ __launch_bounds__(256) void wsplit_kernel(const float* __restrict__ W1,
                                                     unsigned short* __restrict__ Wp) {
    int idx = blockIdx.x * 256 + threadIdx.x;   // 256 cols * 1024 k
    int c = idx >> 10, k = idx & 1023;
    float v = (k < IN_DIM) ? W1[(size_t)k * HIDDEN + c] : 0.0f;
    unsigned short hb = f2bf_rne(v);
    unsigned short lb = f2bf_rne(v - bf2f(hb));
    int ci = c >> 5;
    int step = k >> 4, kk = k & 15;
    int lane = (kk >> 3) * 32 + (c & 31);
    int j = kk & 7;
    size_t base = ((size_t)((step * 8 + ci) * 2) * 64 + lane) * 8 + j;
    Wp[base] = hb;          // plane h
    Wp[base + 512] = lb;    // plane l
}

// ---------------- GEMM1: 64x256 tile, 4 waves, 4 blocks/CU, 2-phase pipeline ----------------
// wave w: rows (w>>1)*32, cols (w&1)*128; 12 MFMA/step/wave.
__global__ __launch_bounds__(256, 4) void gemm1_mfma(const float* __restrict__ X,
                                                     const unsigned short* __restrict__ Wp,
                                                     const float* __restrict__ dinv,
                                                     unsigned short* __restrict__ G1b) {
    __shared__ unsigned short sA[2][2048];   // [mt 2][pl 2][lane 64][8] bf16 = 4KB/buf
    __shared__ unsigned short sB[2][8192];   // [ci 8][pl 2][lane 64][8]  bf16 = 16KB/buf
    const int tid = threadIdx.x;
    const int w   = tid >> 6;
    const int l   = tid & 63;
    const int lr  = l & 31;
    const int lq  = l >> 5;
    const int R   = w >> 1;        // 0..1  (row 32-block)
    const int C   = w & 1;         // 0..1  (col 128-block)
    const int m0  = blockIdx.x * 64;

    // A staging role: thread t -> row rl = t>>2 (0..63), k-quarter ss = t&3 (4 floats)
    const int rl = tid >> 2;
    const int ss = tid & 3;
    const int smt   = rl >> 5;
    const int slane = (ss >> 1) * 32 + (rl & 31);
    const int sidx_h = (smt * 2 + 0) * 512 + slane * 8 + (ss & 1) * 4;   // shorts
    int rg = m0 + rl;
    const float* ap = X + (size_t)(rg < N_NODES ? rg : N_NODES - 1) * IN_DIM + ss * 4;
    const bool svalid_tail = (ss < 2);   // step 62: k = 992 + ss*4, valid only ss<2

    // B staging role: wave w stages chunks w*4+q (q=0..3), 1KB each
    const unsigned short* bsrc = Wp + (size_t)(w * 4) * 512 + l * 8;

    f32x16 acc[4] = {};

    auto stageB = [&](int s, int buf) {
        const unsigned short* src = bsrc + (size_t)s * 8192;
        #pragma unroll
        for (int q = 0; q < 4; ++q)
            GLOAD_LDS16(src + q * 512, &sB[buf][(w * 4 + q) * 512]);
    };
    auto cvtWriteA = [&](float4 f, int buf) {
        unsigned h0 = cvt_pk_bf16(f.x, f.y);
        unsigned h1 = cvt_pk_bf16(f.z, f.w);
        unsigned l0 = cvt_pk_bf16(f.x - __builtin_bit_cast(float, h0 << 16),
                                  f.y - __builtin_bit_cast(float, h0 & 0xFFFF0000u));
        unsigned l1 = cvt_pk_bf16(f.z - __builtin_bit_cast(float, h1 << 16),
                                  f.w - __builtin_bit_cast(float, h1 & 0xFFFF0000u));
        *(uint2*)&sA[buf][sidx_h]       = make_uint2(h0, h1);
        *(uint2*)&sA[buf][sidx_h + 512] = make_uint2(l0, l1);
    };

    // prologue: stage step 0 into buf 0 (k = ss*4 .. +3 <= 15 always valid)
    stageB(0, 0);
    cvtWriteA(*(const float4*)ap, 0);
    __syncthreads();

    #pragma unroll 1
    for (int s = 0; s < NSTEP; ++s) {
        const int buf = s & 1;
        // issue next-step staging loads first (latency hides under MFMA)
        if (s + 1 < NSTEP) stageB(s + 1, buf ^ 1);
        float4 fn = make_float4(0.f, 0.f, 0.f, 0.f);
        if (s + 1 < NSTEP && (s + 1 < NSTEP - 1 || svalid_tail))
            fn = *(const float4*)(ap + (size_t)(s + 1) * 16);

        // fragments from LDS (lane-linear 1KB reads, conflict-free)
        bf16x8 ah = *(const bf16x8*)&sA[buf][(R * 2 + 0) * 512 + l * 8];
        bf16x8 al = *(const bf16x8*)&sA[buf][(R * 2 + 1) * 512 + l * 8];
        bf16x8 bh[4], bl[4];
        #pragma unroll
        for (int ni = 0; ni < 4; ++ni) {
            int ci = C * 4 + ni;
            bh[ni] = *(const bf16x8*)&sB[buf][(ci * 2 + 0) * 512 + l * 8];
            bl[ni] = *(const bf16x8*)&sB[buf][(ci * 2 + 1) * 512 + l * 8];
        }
        #pragma unroll
        for (int ni = 0; ni < 4; ++ni) {
            acc[ni] = __builtin_amdgcn_mfma_f32_32x32x16_bf16(ah, bh[ni], acc[ni], 0, 0, 0);
            acc[ni] = __builtin_amdgcn_mfma_f32_32x32x16_bf16(ah, bl[ni], acc[ni], 0, 0, 0);
            acc[ni] = __builtin_amdgcn_mfma_f32_32x32x16_bf16(al, bh[ni], acc[ni], 0, 0, 0);
        }

        // convert + ds_write next A tile into the other buffer
        if (s + 1 < NSTEP) cvtWriteA(fn, buf ^ 1);
        __syncthreads();   // drains vmcnt (gload_lds) + lgkm; overlapped by 3 other blocks/CU
    }

    // epilogue: C/D layout col=lane&31, row=(r&3)+8*(r>>2)+4*(lane>>5)
    #pragma unroll
    for (int r = 0; r < 16; ++r) {
        int row = m0 + R * 32 + (r & 3) + 8 * (r >> 2) + 4 * lq;
        if (row >= N_NODES) continue;
        float dv = dinv[row];
        #pragma unroll
        for (int ni = 0; ni < 4; ++ni) {
            int col = C * 128 + ni * 32 + lr;
            G1b[(size_t)row * HIDDEN + col] = f2bf_rne(dv * acc[ni][r]);
        }
    }
}

// ---------------- fused agg1 + gemm2 ----------------
__global__ __launch_bounds__(256) void agg1g2_kernel(const unsigned short* __restrict__ G,
                                                     const int* __restrict__ csr,
                                                     const int* __restrict__ rowoff,
                                                     const int* __restrict__ cnt,
                                                     const float* __restrict__ dinv,
                                                     const float* __restrict__ b1,
                                                     const float* __restrict__ W2,
                                                     float* __restrict__ G2) {
    __shared__ float2 wl[HIDDEN];
    int tid = threadIdx.x;
    wl[tid] = make_float2(W2[tid * 2], W2[tid * 2 + 1]);
    __syncthreads();
    int wave = tid >> 6;
    int lane = tid & 63;
    int d = blockIdx.x * 4 + wave;
    if (d >= N_NODES) return;
    int c0 = lane * 4;
    ushort4 sv = *(const ushort4*)&G[(size_t)d * HIDDEN + c0];
    float ax = bf2f(sv.x), ay = bf2f(sv.y), az = bf2f(sv.z), aw = bf2f(sv.w);
    int beg = rowoff[d], num = cnt[d];
    int end = beg + num;
    int e = beg;
    for (; e + 4 <= end; e += 4) {
        int s0 = csr[e], s1 = csr[e + 1], s2 = csr[e + 2], s3 = csr[e + 3];
        ushort4 v0 = *(const ushort4*)&G[(size_t)s0 * HIDDEN + c0];
        ushort4 v1 = *(const ushort4*)&G[(size_t)s1 * HIDDEN + c0];
        ushort4 v2 = *(const ushort4*)&G[(size_t)s2 * HIDDEN + c0];
        ushort4 v3 = *(const ushort4*)&G[(size_t)s3 * HIDDEN + c0];
        ax += bf2f(v0.x); ay += bf2f(v0.y); az += bf2f(v0.z); aw += bf2f(v0.w);
        ax += bf2f(v1.x); ay += bf2f(v1.y); az += bf2f(v1.z); aw += bf2f(v1.w);
        ax += bf2f(v2.x); ay += bf2f(v2.y); az += bf2f(v2.z); aw += bf2f(v2.w);
        ax += bf2f(v3.x); ay += bf2f(v3.y); az += bf2f(v3.z); aw += bf2f(v3.w);
    }
    for (; e < end; ++e) {
        int s = csr[e];
        ushort4 v = *(const ushort4*)&G[(size_t)s * HIDDEN + c0];
        ax += bf2f(v.x); ay += bf2f(v.y); az += bf2f(v.z); aw += bf2f(v.w);
    }
    float dv = dinv[d];
    float4 bb = *(const float4*)&b1[c0];
    float zx = fmaxf(dv * ax + bb.x, 0.f);
    float zy = fmaxf(dv * ay + bb.y, 0.f);
    float zz = fmaxf(dv * az + bb.z, 0.f);
    float zw = fmaxf(dv * aw + bb.w, 0.f);
    float2 w0 = wl[c0], w1 = wl[c0 + 1], w2_ = wl[c0 + 2], w3 = wl[c0 + 3];
    float a0 = zx * w0.x + zy * w1.x + zz * w2_.x + zw * w3.x;
    float a1 = zx * w0.y + zy * w1.y + zz * w2_.y + zw * w3.y;
    #pragma unroll
    for (int off = 32; off; off >>= 1) {
        a0 += __shfl_xor(a0, off, 64);
        a1 += __shfl_xor(a1, off, 64);
    }
    if (lane == 0) {
        G2[d * 2 + 0] = dv * a0;
        G2[d * 2 + 1] = dv * a1;
    }
}

// ---------------- agg2 ----------------
__global__ __launch_bounds__(256) void agg2_kernel(const float* __restrict__ G2,
                                                   const int* __restrict__ csr,
                                                   const int* __restrict__ rowoff,
                                                   const int* __restrict__ cnt,
                                                   const float* __restrict__ dinv,
                                                   const float* __restrict__ b2,
                                                   float* __restrict__ out) {
    int wave = threadIdx.x >> 6, lane = threadIdx.x & 63;
    int d = blockIdx.x * 4 + wave;
    if (d >= N_NODES) return;
    int beg = rowoff[d], num = cnt[d];
    float a0 = 0.f, a1 = 0.f;
    for (int e = lane; e < num; e += 64) {
        int s = csr[beg + e];
        float2 g = *(const float2*)&G2[s * 2];
        a0 += g.x; a1 += g.y;
    }
    #pragma unroll
    for (int off = 32; off; off >>= 1) {
        a0 += __shfl_xor(a0, off, 64);
        a1 += __shfl_xor(a1, off, 64);
    }
    if (lane == 0) {
        float2 self = *(const float2*)&G2[d * 2];
        float dv = dinv[d];
        out[d * 2 + 0] = dv * (a0 + self.x) + b2[0];
        out[d * 2 + 1] = dv * (a1 + self.y) + b2[1];
    }
}

// ---------------- workspace layout (bytes) ----------------
#define OFF_CNT     0u
#define OFF_ROWOFF  262144u
#define OFF_CURSOR  524288u
#define OFF_DINV    786432u
#define OFF_BSUM    1048576u
#define OFF_CSR     1310720u
#define OFF_WP      8388608u     // 1 MB packed per-step (h+l)
#define OFF_G1B     9437184u
#define OFF_G2      35651584u
// total ~36.1 MB

extern "C" void kernel_launch(void* const* d_in, const int* in_sizes, int n_in,
                              void* d_out, int out_size, void* d_ws, size_t ws_size,
                              hipStream_t stream) {
    const float* x  = (const float*)d_in[0];
    const float* W1 = (const float*)d_in[1];
    const float* b1 = (const float*)d_in[2];
    const float* W2 = (const float*)d_in[3];
    const float* b2 = (const float*)d_in[4];
    const int*   ei = (const int*)d_in[5];

    char* ws = (char*)d_ws;
    int*   cnt    = (int*)  (ws + OFF_CNT);
    int*   rowoff = (int*)  (ws + OFF_ROWOFF);
    int*   cursor = (int*)  (ws + OFF_CURSOR);
    float* dinv   = (float*)(ws + OFF_DINV);
    int*   bsum   = (int*)  (ws + OFF_BSUM);
    int*   csr    = (int*)  (ws + OFF_CSR);
    unsigned short* wp  = (unsigned short*)(ws + OFF_WP);
    unsigned short* g1b = (unsigned short*)(ws + OFF_G1B);
    float* g2     = (float*)(ws + OFF_G2);
    float* out    = (float*)d_out;

    hipMemsetAsync(cnt, 0, N_NODES * sizeof(int), stream);
    hist_kernel<<<2048, 256, 0, stream>>>(ei, cnt);
    scan_sums<<<NBLK, 256, 0, stream>>>(cnt, bsum);
    scan_top<<<1, 256, 0, stream>>>(bsum);
    scan_write<<<NBLK, 256, 0, stream>>>(cnt, bsum, rowoff, cursor, dinv);
    scatter_kernel<<<2048, 256, 0, stream>>>(ei, cursor, csr);
    wsplit_kernel<<<1024, 256, 0, stream>>>(W1, wp);

    gemm1_mfma<<<(N_NODES + 63) / 64, 256, 0, stream>>>(x, wp, dinv, g1b);

    agg1g2_kernel<<<(N_NODES + 3) / 4, 256, 0, stream>>>(g1b, csr, rowoff, cnt, dinv, b1, W2, g2);
    agg2_kernel<<<(N_NODES + 3) / 4, 256, 0, stream>>>(g2, csr, rowoff, cnt, dinv, b2, out);
}

// Round 8
// 422.390 us; speedup vs baseline: 1.5740x; 1.0311x over previous
//
#include <hip/hip_runtime.h>
#include <math.h>

#define N_NODES 50000
#define IN_DIM  1000
#define HIDDEN  256
#define N_EDGES 1600000
#define NBLK    196      // ceil(50000/256)
#define NSTEP   63       // ceil(1000/16)

typedef short bf16x8 __attribute__((ext_vector_type(8)));
typedef float f32x16 __attribute__((ext_vector_type(16)));

__device__ __forceinline__ unsigned short f2bf_rne(float f) {
    unsigned u = __builtin_bit_cast(unsigned, f);
    unsigned r = (u + 0x7FFFu + ((u >> 16) & 1u)) >> 16;
    return (unsigned short)r;
}
__device__ __forceinline__ float bf2f(unsigned short b) {
    unsigned u = ((unsigned)b) << 16;
    return __builtin_bit_cast(float, u);
}
__device__ __forceinline__ unsigned cvt_pk_bf16(float a, float b) {
    unsigned r;
    asm("v_cvt_pk_bf16_f32 %0, %1, %2" : "=v"(r) : "v"(a), "v"(b));
    return r;   // [15:0]=bf16(a), [31:16]=bf16(b)
}
#define GLOAD_LDS16(gp, lp) \
    __builtin_amdgcn_global_load_lds((const __attribute__((address_space(1))) unsigned*)(gp), \
                                     (__attribute__((address_space(3))) unsigned*)(lp), 16, 0, 0)

// ---------------- degree histogram ----------------
__global__ void hist_kernel(const int* __restrict__ ei, int* __restrict__ cnt) {
    int e = blockIdx.x * blockDim.x + threadIdx.x;
    int stride = gridDim.x * blockDim.x;
    for (; e < N_EDGES; e += stride) {
        int d = ei[N_EDGES + e];
        if ((unsigned)d < N_NODES) atomicAdd(&cnt[d], 1);
    }
}

// ---------------- 3-phase scan ----------------
__global__ __launch_bounds__(256) void scan_sums(const int* __restrict__ cnt, int* __restrict__ bsum) {
    __shared__ int s[256];
    int t = threadIdx.x;
    int i = blockIdx.x * 256 + t;
    s[t] = (i < N_NODES) ? cnt[i] : 0;
    __syncthreads();
    #pragma unroll
    for (int off = 128; off > 0; off >>= 1) {
        if (t < off) s[t] += s[t + off];
        __syncthreads();
    }
    if (t == 0) bsum[blockIdx.x] = s[0];
}

__global__ __launch_bounds__(256) void scan_top(int* __restrict__ bsum) {
    __shared__ int s[256];
    int t = threadIdx.x;
    int v = (t < NBLK) ? bsum[t] : 0;
    s[t] = v;
    __syncthreads();
    for (int off = 1; off < 256; off <<= 1) {
        int x = (t >= off) ? s[t - off] : 0;
        __syncthreads();
        s[t] += x;
        __syncthreads();
    }
    if (t < NBLK) bsum[t] = s[t] - v;   // exclusive
}

__global__ __launch_bounds__(256) void scan_write(const int* __restrict__ cnt, const int* __restrict__ bsum,
                                                  int* __restrict__ rowoff, int* __restrict__ cursor,
                                                  float* __restrict__ dinv) {
    __shared__ int s[256];
    int t = threadIdx.x;
    int i = blockIdx.x * 256 + t;
    int v = (i < N_NODES) ? cnt[i] : 0;
    s[t] = v;
    __syncthreads();
    for (int off = 1; off < 256; off <<= 1) {
        int x = (t >= off) ? s[t - off] : 0;
        __syncthreads();
        s[t] += x;
        __syncthreads();
    }
    if (i < N_NODES) {
        int ro = bsum[blockIdx.x] + s[t] - v;   // exclusive
        rowoff[i] = ro;
        cursor[i] = ro;
        dinv[i]  = rsqrtf((float)v + 1.0f);
    }
}

// ---------------- counting-sort scatter ----------------
__global__ void scatter_kernel(const int* __restrict__ ei,
                               int* __restrict__ cursor, int* __restrict__ csr) {
    int e = blockIdx.x * blockDim.x + threadIdx.x;
    int stride = gridDim.x * blockDim.x;
    for (; e < N_EDGES; e += stride) {
        int s = ei[e];
        int d = ei[N_EDGES + e];
        if ((unsigned)d < N_NODES && (unsigned)s < N_NODES) {
            int pos = atomicAdd(&cursor[d], 1);
            csr[pos] = s;
        }
    }
}

// ---------------- W1 split + pack per-step fragment blocks ----------------
// Wp[step 0..63][ci 0..7][pl 0..1][lane 0..63][j 0..7] (bf16), 16 KB per step.
// element: col = ci*32 + (lane&31), k = step*16 + (lane>>5)*8 + j
__global__ __launch_bounds__(256) void wsplit_kernel(const float* __restrict__ W1,
                                                     unsigned short* __restrict__ Wp) {
    int idx = blockIdx.x * 256 + threadIdx.x;   // 256 cols * 1024 k
    int c = idx >> 10, k = idx & 1023;
    float v = (k < IN_DIM) ? W1[(size_t)k * HIDDEN + c] : 0.0f;
    unsigned short hb = f2bf_rne(v);
    unsigned short lb = f2bf_rne(v - bf2f(hb));
    int ci = c >> 5;
    int step = k >> 4, kk = k & 15;
    int lane = (kk >> 3) * 32 + (c & 31);
    int j = kk & 7;
    size_t base = ((size_t)((step * 8 + ci) * 2) * 64 + lane) * 8 + j;
    Wp[base] = hb;          // plane h
    Wp[base + 512] = lb;    // plane l
}

// ---------------- GEMM1: 64x256 tile, 4 waves, 4 blocks/CU ----------------
// A single bf16 plane (X quantized once); W hi+lo -> 2 MFMA products, 8/wave/step.
// A global load register-pipelined one full step ahead (consumed after a barrier
// that already drained its vmcnt -> zero exposed latency).
__global__ __launch_bounds__(256, 4) void gemm1_mfma(const float* __restrict__ X,
                                                     const unsigned short* __restrict__ Wp,
                                                     const float* __restrict__ dinv,
                                                     unsigned short* __restrict__ G1b) {
    __shared__ unsigned short sA[2][1024];   // [mt 2][lane 64][8] bf16 = 2KB/buf
    __shared__ unsigned short sB[2][8192];   // [ci 8][pl 2][lane 64][8] bf16 = 16KB/buf
    const int tid = threadIdx.x;
    const int w   = tid >> 6;
    const int l   = tid & 63;
    const int lr  = l & 31;
    const int lq  = l >> 5;
    const int R   = w >> 1;        // row 32-block
    const int C   = w & 1;         // col 128-block
    const int m0  = blockIdx.x * 64;

    // A staging role: thread t -> row rl = t>>2, k-quarter ss = t&3 (4 floats -> 2 cvt_pk -> 8B)
    const int rl = tid >> 2;
    const int ss = tid & 3;
    const int smt   = rl >> 5;
    const int slane = (ss >> 1) * 32 + (rl & 31);
    const int sidx  = smt * 512 + slane * 8 + (ss & 1) * 4;   // shorts
    int rg = m0 + rl;
    const float* ap = X + (size_t)(rg < N_NODES ? rg : N_NODES - 1) * IN_DIM + ss * 4;
    const bool svalid_tail = (ss < 2);   // step 62: k = 992+ss*4, +3 must be <1000

    // B staging role: wave w stages chunks w*4+q (q=0..3), 1KB each
    const unsigned short* bsrc = Wp + (size_t)(w * 4) * 512 + l * 8;

    f32x16 acc[4] = {};

    auto stageB = [&](int s, int buf) {
        const unsigned short* src = bsrc + (size_t)s * 8192;
        #pragma unroll
        for (int q = 0; q < 4; ++q)
            GLOAD_LDS16(src + q * 512, &sB[buf][(w * 4 + q) * 512]);
    };
    auto cvtWriteA = [&](float4 f, int buf) {
        unsigned h0 = cvt_pk_bf16(f.x, f.y);
        unsigned h1 = cvt_pk_bf16(f.z, f.w);
        *(uint2*)&sA[buf][sidx] = make_uint2(h0, h1);
    };

    // prologue: stage step 0 into buf 0; issue A[1] load
    stageB(0, 0);
    cvtWriteA(*(const float4*)ap, 0);
    float4 rA = make_float4(0.f, 0.f, 0.f, 0.f);
    if (1 < NSTEP) rA = *(const float4*)(ap + 16);
    __syncthreads();

    #pragma unroll 1
    for (int s = 0; s < NSTEP; ++s) {
        const int buf = s & 1;
        // top-of-step: issue all staging for s+1 / load for s+2
        if (s + 1 < NSTEP) stageB(s + 1, buf ^ 1);
        float4 rN = make_float4(0.f, 0.f, 0.f, 0.f);
        if (s + 2 < NSTEP && (s + 2 < NSTEP - 1 || svalid_tail))
            rN = *(const float4*)(ap + (size_t)(s + 2) * 16);
        if (s + 1 < NSTEP) cvtWriteA(rA, buf ^ 1);   // rA arrived >= 1 barrier ago

        // fragments from LDS (lane-linear, conflict-free)
        bf16x8 ah = *(const bf16x8*)&sA[buf][R * 512 + l * 8];
        bf16x8 bh[4], bl[4];
        #pragma unroll
        for (int ni = 0; ni < 4; ++ni) {
            int ci = C * 4 + ni;
            bh[ni] = *(const bf16x8*)&sB[buf][(ci * 2 + 0) * 512 + l * 8];
            bl[ni] = *(const bf16x8*)&sB[buf][(ci * 2 + 1) * 512 + l * 8];
        }
        #pragma unroll
        for (int ni = 0; ni < 4; ++ni) {
            acc[ni] = __builtin_amdgcn_mfma_f32_32x32x16_bf16(ah, bh[ni], acc[ni], 0, 0, 0);
            acc[ni] = __builtin_amdgcn_mfma_f32_32x32x16_bf16(ah, bl[ni], acc[ni], 0, 0, 0);
        }
        rA = rN;
        __syncthreads();
    }

    // epilogue: C/D layout col=lane&31, row=(r&3)+8*(r>>2)+4*(lane>>5)
    #pragma unroll
    for (int r = 0; r < 16; ++r) {
        int row = m0 + R * 32 + (r & 3) + 8 * (r >> 2) + 4 * lq;
        if (row >= N_NODES) continue;
        float dv = dinv[row];
        #pragma unroll
        for (int ni = 0; ni < 4; ++ni) {
            int col = C * 128 + ni * 32 + lr;
            G1b[(size_t)row * HIDDEN + col] = f2bf_rne(dv * acc[ni][r]);
        }
    }
}

// ---------------- fused agg1 + gemm2 ----------------
__global__ __launch_bounds__(256) void agg1g2_kernel(const unsigned short* __restrict__ G,
                                                     const int* __restrict__ csr,
                                                     const int* __restrict__ rowoff,
                                                     const int* __restrict__ cnt,
                                                     const float* __restrict__ dinv,
                                                     const float* __restrict__ b1,
                                                     const float* __restrict__ W2,
                                                     float* __restrict__ G2) {
    __shared__ float2 wl[HIDDEN];
    int tid = threadIdx.x;
    wl[tid] = make_float2(W2[tid * 2], W2[tid * 2 + 1]);
    __syncthreads();
    int wave = tid >> 6;
    int lane = tid & 63;
    int d = blockIdx.x * 4 + wave;
    if (d >= N_NODES) return;
    int c0 = lane * 4;
    ushort4 sv = *(const ushort4*)&G[(size_t)d * HIDDEN + c0];
    float ax = bf2f(sv.x), ay = bf2f(sv.y), az = bf2f(sv.z), aw = bf2f(sv.w);
    int beg = rowoff[d], num = cnt[d];
    int end = beg + num;
    int e = beg;
    // 8-deep unroll: more outstanding gathers (adds stay in CSR order)
    for (; e + 8 <= end; e += 8) {
        int s0 = csr[e], s1 = csr[e+1], s2 = csr[e+2], s3 = csr[e+3];
        int s4 = csr[e+4], s5 = csr[e+5], s6 = csr[e+6], s7 = csr[e+7];
        ushort4 v0 = *(const ushort4*)&G[(size_t)s0 * HIDDEN + c0];
        ushort4 v1 = *(const ushort4*)&G[(size_t)s1 * HIDDEN + c0];
        ushort4 v2 = *(const ushort4*)&G[(size_t)s2 * HIDDEN + c0];
        ushort4 v3 = *(const ushort4*)&G[(size_t)s3 * HIDDEN + c0];
        ushort4 v4 = *(const ushort4*)&G[(size_t)s4 * HIDDEN + c0];
        ushort4 v5 = *(const ushort4*)&G[(size_t)s5 * HIDDEN + c0];
        ushort4 v6 = *(const ushort4*)&G[(size_t)s6 * HIDDEN + c0];
        ushort4 v7 = *(const ushort4*)&G[(size_t)s7 * HIDDEN + c0];
        ax += bf2f(v0.x); ay += bf2f(v0.y); az += bf2f(v0.z); aw += bf2f(v0.w);
        ax += bf2f(v1.x); ay += bf2f(v1.y); az += bf2f(v1.z); aw += bf2f(v1.w);
        ax += bf2f(v2.x); ay += bf2f(v2.y); az += bf2f(v2.z); aw += bf2f(v2.w);
        ax += bf2f(v3.x); ay += bf2f(v3.y); az += bf2f(v3.z); aw += bf2f(v3.w);
        ax += bf2f(v4.x); ay += bf2f(v4.y); az += bf2f(v4.z); aw += bf2f(v4.w);
        ax += bf2f(v5.x); ay += bf2f(v5.y); az += bf2f(v5.z); aw += bf2f(v5.w);
        ax += bf2f(v6.x); ay += bf2f(v6.y); az += bf2f(v6.z); aw += bf2f(v6.w);
        ax += bf2f(v7.x); ay += bf2f(v7.y); az += bf2f(v7.z); aw += bf2f(v7.w);
    }
    for (; e < end; ++e) {
        int s = csr[e];
        ushort4 v = *(const ushort4*)&G[(size_t)s * HIDDEN + c0];
        ax += bf2f(v.x); ay += bf2f(v.y); az += bf2f(v.z); aw += bf2f(v.w);
    }
    float dv = dinv[d];
    float4 bb = *(const float4*)&b1[c0];
    float zx = fmaxf(dv * ax + bb.x, 0.f);
    float zy = fmaxf(dv * ay + bb.y, 0.f);
    float zz = fmaxf(dv * az + bb.z, 0.f);
    float zw = fmaxf(dv * aw + bb.w, 0.f);
    float2 w0 = wl[c0], w1 = wl[c0 + 1], w2_ = wl[c0 + 2], w3 = wl[c0 + 3];
    float a0 = zx * w0.x + zy * w1.x + zz * w2_.x + zw * w3.x;
    float a1 = zx * w0.y + zy * w1.y + zz * w2_.y + zw * w3.y;
    #pragma unroll
    for (int off = 32; off; off >>= 1) {
        a0 += __shfl_xor(a0, off, 64);
        a1 += __shfl_xor(a1, off, 64);
    }
    if (lane == 0) {
        G2[d * 2 + 0] = dv * a0;
        G2[d * 2 + 1] = dv * a1;
    }
}

// ---------------- agg2 ----------------
__global__ __launch_bounds__(256) void agg2_kernel(const float* __restrict__ G2,
                                                   const int* __restrict__ csr,
                                                   const int* __restrict__ rowoff,
                                                   const int* __restrict__ cnt,
                                                   const float* __restrict__ dinv,
                                                   const float* __restrict__ b2,
                                                   float* __restrict__ out) {
    int wave = threadIdx.x >> 6, lane = threadIdx.x & 63;
    int d = blockIdx.x * 4 + wave;
    if (d >= N_NODES) return;
    int beg = rowoff[d], num = cnt[d];
    float a0 = 0.f, a1 = 0.f;
    for (int e = lane; e < num; e += 64) {
        int s = csr[beg + e];
        float2 g = *(const float2*)&G2[s * 2];
        a0 += g.x; a1 += g.y;
    }
    #pragma unroll
    for (int off = 32; off; off >>= 1) {
        a0 += __shfl_xor(a0, off, 64);
        a1 += __shfl_xor(a1, off, 64);
    }
    if (lane == 0) {
        float2 self = *(const float2*)&G2[d * 2];
        float dv = dinv[d];
        out[d * 2 + 0] = dv * (a0 + self.x) + b2[0];
        out[d * 2 + 1] = dv * (a1 + self.y) + b2[1];
    }
}

// ---------------- workspace layout (bytes) ----------------
#define OFF_CNT     0u
#define OFF_ROWOFF  262144u
#define OFF_CURSOR  524288u
#define OFF_DINV    786432u
#define OFF_BSUM    1048576u
#define OFF_CSR     1310720u
#define OFF_WP      8388608u     // 1 MB packed per-step (h+l)
#define OFF_G1B     9437184u
#define OFF_G2      35651584u
// total ~36.1 MB

extern "C" void kernel_launch(void* const* d_in, const int* in_sizes, int n_in,
                              void* d_out, int out_size, void* d_ws, size_t ws_size,
                              hipStream_t stream) {
    const float* x  = (const float*)d_in[0];
    const float* W1 = (const float*)d_in[1];
    const float* b1 = (const float*)d_in[2];
    const float* W2 = (const float*)d_in[3];
    const float* b2 = (const float*)d_in[4];
    const int*   ei = (const int*)d_in[5];

    char* ws = (char*)d_ws;
    int*   cnt    = (int*)  (ws + OFF_CNT);
    int*   rowoff = (int*)  (ws + OFF_ROWOFF);
    int*   cursor = (int*)  (ws + OFF_CURSOR);
    float* dinv   = (float*)(ws + OFF_DINV);
    int*   bsum   = (int*)  (ws + OFF_BSUM);
    int*   csr    = (int*)  (ws + OFF_CSR);
    unsigned short* wp  = (unsigned short*)(ws + OFF_WP);
    unsigned short* g1b = (unsigned short*)(ws + OFF_G1B);
    float* g2     = (float*)(ws + OFF_G2);
    float* out    = (float*)d_out;

    hipMemsetAsync(cnt, 0, N_NODES * sizeof(int), stream);
    hist_kernel<<<2048, 256, 0, stream>>>(ei, cnt);
    scan_sums<<<NBLK, 256, 0, stream>>>(cnt, bsum);
    scan_top<<<1, 256, 0, stream>>>(bsum);
    scan_write<<<NBLK, 256, 0, stream>>>(cnt, bsum, rowoff, cursor, dinv);
    scatter_kernel<<<2048, 256, 0, stream>>>(ei, cursor, csr);
    wsplit_kernel<<<1024, 256, 0, stream>>>(W1, wp);

    gemm1_mfma<<<(N_NODES + 63) / 64, 256, 0, stream>>>(x, wp, dinv, g1b);

    agg1g2_kernel<<<(N_NODES + 3) / 4, 256, 0, stream>>>(g1b, csr, rowoff, cnt, dinv, b1, W2, g2);
    agg2_kernel<<<(N_NODES + 3) / 4, 256, 0, stream>>>(g2, csr, rowoff, cnt, dinv, b2, out);
}